// Round 1
// baseline (95.838 us; speedup 1.0000x reference)
//
#include <hip/hip_runtime.h>

// S6 selective scan: BT=8, L=8192, F=128, N=16
// y[b,t,f] = sum_n h[b,t,f,n]*C[b,t,n],  h = dA*h + dB*x  (diagonal A)
//
// Pipeline:
//   k_pre       : x @ {Wb,Wc,Wd} -> G[token][48] = {dA[16], dB[16], C[16]}
//   k_local     : per-(b,chunk) local scan (h0=0) -> q[b,c,f,n], P[b,c,n]
//   k_chunkscan : scan over chunks -> Hin[b,c,f,n] (state entering chunk c)
//   k_final     : replay local scan seeded with Hin, write y

#define BTc   8
#define Lseq  8192
#define Fdim  128
#define Ndim  16
#define CH    128          // number of chunks
#define LC    64           // Lseq / CH

__global__ __launch_bounds__(256) void k_pre(
    const float* __restrict__ x,
    const float* __restrict__ Wb, const float* __restrict__ bb,
    const float* __restrict__ Wc, const float* __restrict__ bc,
    const float* __restrict__ Wd, const float* __restrict__ bd,
    const float* __restrict__ A,  float* __restrict__ G)
{
    __shared__ float Wl[33][128];   // transposed weights: Wl[j][k]
    int tid = threadIdx.x;
    for (int idx = tid; idx < 33 * 128; idx += 256) {
        int j = idx >> 7, k = idx & 127;
        float v;
        if (j < 16)      v = Wb[k * 16 + j];
        else if (j < 32) v = Wc[k * 16 + (j - 16)];
        else             v = Wd[k];
        Wl[j][k] = v;
    }
    __syncthreads();

    int token = blockIdx.x * 256 + tid;         // 65536 tokens total
    const float* xr = x + (size_t)token * 128;

    float acc[33];
#pragma unroll
    for (int j = 0; j < 33; j++) acc[j] = 0.f;

#pragma unroll 2
    for (int kk = 0; kk < 32; kk++) {
        float4 xv = reinterpret_cast<const float4*>(xr)[kk];
#pragma unroll
        for (int j = 0; j < 33; j++) {
            float4 w = *reinterpret_cast<const float4*>(&Wl[j][kk * 4]);
            acc[j] = fmaf(xv.x, w.x, acc[j]);
            acc[j] = fmaf(xv.y, w.y, acc[j]);
            acc[j] = fmaf(xv.z, w.z, acc[j]);
            acc[j] = fmaf(xv.w, w.w, acc[j]);
        }
    }

    // softplus, overflow-safe: max(v,0) + log1p(exp(-|v|))
    float v = acc[32] + bd[0];
    float delta = fmaxf(v, 0.f) + log1pf(expf(-fabsf(v)));

    float out[48];
#pragma unroll
    for (int n = 0; n < 16; n++) {
        float An = A[n];
        float Bn = acc[n] + bb[n];
        float Cn = acc[16 + n] + bc[n];
        float dA = expf(delta * An);
        float dB = (dA - 1.f) / An * Bn;
        out[n]      = dA;
        out[16 + n] = dB;
        out[32 + n] = Cn;
    }
    float4* Gr = reinterpret_cast<float4*>(G + (size_t)token * 48);
#pragma unroll
    for (int q = 0; q < 12; q++)
        Gr[q] = make_float4(out[4*q], out[4*q+1], out[4*q+2], out[4*q+3]);
}

__global__ __launch_bounds__(128) void k_local(
    const float* __restrict__ x, const float* __restrict__ G,
    float* __restrict__ q, float* __restrict__ P)
{
    __shared__ float Gl[LC][48];
    int c = blockIdx.x, b = blockIdx.y;
    int f = threadIdx.x;
    int t0 = c * LC;
    const float* Gc = G + (size_t)(b * Lseq + t0) * 48;
    for (int idx = f; idx < LC * 48 / 4; idx += 128)
        reinterpret_cast<float4*>(&Gl[0][0])[idx] =
            reinterpret_cast<const float4*>(Gc)[idx];
    __syncthreads();

    float h[16], pr[16];
#pragma unroll
    for (int n = 0; n < 16; n++) { h[n] = 0.f; pr[n] = 1.f; }

    const float* xp = x + (size_t)(b * Lseq + t0) * 128 + f;
    for (int t = 0; t < LC; t++) {
        float xv = xp[t * 128];
#pragma unroll
        for (int n = 0; n < 16; n++) {
            float dA = Gl[t][n];
            float dB = Gl[t][16 + n];
            h[n]  = fmaf(dA, h[n], dB * xv);
            pr[n] *= dA;
        }
    }

    float* qp = q + ((size_t)(b * CH + c) * 128 + f) * 16;
#pragma unroll
    for (int n = 0; n < 16; n++) qp[n] = h[n];
    if (f == 0) {
        float* Pp = P + (size_t)(b * CH + c) * 16;
#pragma unroll
        for (int n = 0; n < 16; n++) Pp[n] = pr[n];
    }
}

__global__ __launch_bounds__(256) void k_chunkscan(
    const float* __restrict__ q, const float* __restrict__ P,
    float* __restrict__ Hin)
{
    int id = blockIdx.x * 256 + threadIdx.x;   // 16384 = 8*128*16
    int b  = id >> 11;
    int fn = id & 2047;
    int n  = id & 15;
    float H = 0.f;
    for (int c = 0; c < CH; c++) {
        size_t base = (size_t)(b * CH + c);
        Hin[base * 2048 + fn] = H;
        float Pc = P[base * 16 + n];
        float qc = q[base * 2048 + fn];
        H = fmaf(Pc, H, qc);
    }
}

__global__ __launch_bounds__(128) void k_final(
    const float* __restrict__ x, const float* __restrict__ G,
    const float* __restrict__ Hin, float* __restrict__ y)
{
    __shared__ float Gl[LC][48];
    int c = blockIdx.x, b = blockIdx.y;
    int f = threadIdx.x;
    int t0 = c * LC;
    const float* Gc = G + (size_t)(b * Lseq + t0) * 48;
    for (int idx = f; idx < LC * 48 / 4; idx += 128)
        reinterpret_cast<float4*>(&Gl[0][0])[idx] =
            reinterpret_cast<const float4*>(Gc)[idx];
    __syncthreads();

    float h[16];
    const float* hp = Hin + ((size_t)(b * CH + c) * 128 + f) * 16;
#pragma unroll
    for (int n = 0; n < 16; n++) h[n] = hp[n];

    const float* xp = x + (size_t)(b * Lseq + t0) * 128 + f;
    float*       yp = y + (size_t)(b * Lseq + t0) * 128 + f;
    for (int t = 0; t < LC; t++) {
        float xv  = xp[t * 128];
        float acc = 0.f;
#pragma unroll
        for (int n = 0; n < 16; n++) {
            float dA = Gl[t][n];
            float dB = Gl[t][16 + n];
            float Cn = Gl[t][32 + n];
            h[n] = fmaf(dA, h[n], dB * xv);
            acc  = fmaf(Cn, h[n], acc);
        }
        yp[t * 128] = acc;
    }
}

extern "C" void kernel_launch(void* const* d_in, const int* in_sizes, int n_in,
                              void* d_out, int out_size, void* d_ws, size_t ws_size,
                              hipStream_t stream) {
    const float* x  = (const float*)d_in[0];
    const float* Wb = (const float*)d_in[1];
    const float* bb = (const float*)d_in[2];
    const float* Wc = (const float*)d_in[3];
    const float* bc = (const float*)d_in[4];
    const float* Wd = (const float*)d_in[5];
    const float* bd = (const float*)d_in[6];
    const float* A  = (const float*)d_in[7];
    float* y = (float*)d_out;

    float* G   = (float*)d_ws;                             // 65536*48   = 12.6 MB
    float* q   = G   + (size_t)BTc * Lseq * 48;            // 8*128*2048 = 8.4 MB
    float* P   = q   + (size_t)BTc * CH * Fdim * Ndim;     // 8*128*16   = 64 KB
    float* Hin = P   + (size_t)BTc * CH * Ndim;            // 8*128*2048 = 8.4 MB

    k_pre<<<dim3(BTc * Lseq / 256), 256, 0, stream>>>(x, Wb, bb, Wc, bc, Wd, bd, A, G);
    k_local<<<dim3(CH, BTc), 128, 0, stream>>>(x, G, q, P);
    k_chunkscan<<<dim3(BTc * Fdim * Ndim / 256), 256, 0, stream>>>(q, P, Hin);
    k_final<<<dim3(CH, BTc), 128, 0, stream>>>(x, G, Hin, y);
}